// Round 2
// baseline (121.067 us; speedup 1.0000x reference)
//
#include <hip/hip_runtime.h>
#include <math.h>
#include <stdint.h>

#define NM 8          // nmul
#define NPAR 12
#define PFD 8         // prefetch depth in timesteps (rolling register buffer)

typedef float v2f __attribute__((ext_vector_type(2)));

static __device__ __forceinline__ v2f bc(float s){ v2f r; r.x = s; r.y = s; return r; }
static __device__ __forceinline__ v2f vmin(v2f a, v2f b){ v2f r; r.x=fminf(a.x,b.x); r.y=fminf(a.y,b.y); return r; }
static __device__ __forceinline__ v2f vmax(v2f a, v2f b){ v2f r; r.x=fmaxf(a.x,b.x); r.y=fmaxf(a.y,b.y); return r; }
static __device__ __forceinline__ v2f vmins(v2f a, float b){ v2f r; r.x=fminf(a.x,b); r.y=fminf(a.y,b); return r; }
static __device__ __forceinline__ v2f vmaxs(v2f a, float b){ v2f r; r.x=fmaxf(a.x,b); r.y=fmaxf(a.y,b); return r; }
// min3: clang fuses nested fminf into v_min3_f32
static __device__ __forceinline__ v2f vmin3(v2f a, v2f b, v2f c){
    v2f r; r.x=fminf(fminf(a.x,b.x),c.x); r.y=fminf(fminf(a.y,b.y),c.y); return r;
}

__global__ __launch_bounds__(64, 1) void hbv_kernel(
    const float* __restrict__ x,      // [T, G, 3]  (prcp, tmean, pet)
    const float* __restrict__ praw,   // [1, G, 12, NM] in [0,1)
    float* __restrict__ out,          // [T, G, NM]
    int G, int T)
{
    const int tid = blockIdx.x * blockDim.x + threadIdx.x;
    const int npair = G * (NM / 2);          // 2 chains (m, m+1) per thread
    if (tid >= npair) return;
    const int g  = tid >> 2;                 // / (NM/2)
    const int mp = (tid & 3) << 1;           // m0 = 0,2,4,6

    // Parameter bounds: BETA, FC, K0, K1, K2, LP, PERC, UZL, TT, CFMAX, CFR, CWH
    const float lb[NPAR] = {1.0f, 50.0f, 0.05f, 0.01f, 0.001f, 0.2f, 0.0f, 0.0f, -2.5f, 0.5f, 0.0f, 0.0f};
    const float ub[NPAR] = {6.0f, 1000.0f, 0.9f, 0.5f, 0.2f, 1.0f, 10.0f, 100.0f, 2.5f, 10.0f, 0.1f, 0.2f};

    v2f p[NPAR];
    const float* pr = praw + (size_t)g * (NPAR * NM) + mp;
    #pragma unroll
    for (int i = 0; i < NPAR; ++i) {
        v2f r = *(const v2f*)(pr + i * NM);  // 8B-aligned: mp is even
        p[i] = r * (ub[i] - lb[i]) + lb[i];
    }

    const v2f BETA = p[0], FC = p[1], K0 = p[2], K1 = p[3], K2 = p[4], LP = p[5],
              PERCc = p[6], UZL = p[7], TT = p[8], CFMAX = p[9], CFR = p[10], CWH = p[11];

    const v2f one = bc(1.0f);
    const v2f invFC       = one / FC;
    const v2f invLPFC     = one / (LP * FC);
    const v2f CFRCFMAX    = CFR * CFMAX;
    const v2f OMK1        = one - K1;        // 1 - K1
    const v2f OMK2        = one - K2;        // 1 - K2

    v2f SNOWPACK = bc(0.001f), MELTWATER = bc(0.001f),
        SM = bc(0.001f), SUZ = bc(0.001f), SLZ = bc(0.001f);

    // 32-bit byte offsets from uniform (SGPR) bases -> saddr-form loads/stores
    const char* xb = (const char*)x;
    char* ob = (char*)out;
    const uint32_t xstep = (uint32_t)G * 12u;                 // bytes per timestep in x
    const uint32_t xoff0 = (uint32_t)g * 12u;
    const uint32_t xmax  = xoff0 + (uint32_t)(T - 1) * xstep; // clamp target (last valid row)
    uint32_t ooff = (uint32_t)(g * NM + mp) * 4u;             // 8B-aligned (mp even)
    const uint32_t ostep = (uint32_t)(G * NM) * 4u;

    // --- rolling forcing buffer with state-independent precompute hoisted in ---
    // Per slot: RAIN, SNOW (rain/snow split), meltcap, refrcap (pre-clamped), PET
    v2f RAINb[PFD], SNOWb[PFD], MCb[PFD], RCb[PFD];
    float PETb[PFD];
    uint32_t poff = xoff0;

    // refill slot d from byte offset poff, then advance poff with branch-free clamp
    #define REFILL(d)                                                          \
    {                                                                          \
        const float P_   = *(const float*)(xb + poff);                         \
        const float Tt_  = *(const float*)(xb + poff + 4);                     \
        PETb[d]          = *(const float*)(xb + poff + 8);                     \
        v2f rain;                                                              \
        rain.x = (Tt_ >= TT.x) ? P_ : 0.0f;                                    \
        rain.y = (Tt_ >= TT.y) ? P_ : 0.0f;                                    \
        RAINb[d] = rain;                                                       \
        SNOWb[d] = bc(P_) - rain;                                              \
        v2f dT = bc(Tt_) - TT;                                                 \
        MCb[d] = vmaxs(CFMAX * dT, 0.0f);                                      \
        RCb[d] = vmaxs(CFRCFMAX * (TT - bc(Tt_)), 0.0f);                       \
        uint32_t nx_ = poff + xstep;                                           \
        poff = (nx_ < xmax) ? nx_ : xmax;                                      \
    }

    #pragma unroll
    for (int d = 0; d < PFD; ++d) REFILL(d)

    auto step = [&](v2f RAIN, v2f SNOW, v2f meltcap, v2f refrcap, float PET) -> v2f {
        // --- snow routine (caps pre-clamped at refill) ---
        SNOWPACK += SNOW;
        const v2f melt = vmin(meltcap, SNOWPACK);
        MELTWATER += melt;
        SNOWPACK  -= melt;
        const v2f refr = vmin(refrcap, MELTWATER);
        SNOWPACK  += refr;
        MELTWATER -= refr;
        const v2f cwhsp  = CWH * SNOWPACK;
        const v2f tosoil = vmaxs(MELTWATER - cwhsp, 0.0f);
        MELTWATER = vmin(MELTWATER, cwhsp);          // == MELTWATER - tosoil

        // --- soil routine ---
        const v2f ratio = SM * invFC;                // in (0, 1] (SM <= FC invariant)
        v2f bl;
        bl.x = fminf(BETA.x * __builtin_amdgcn_logf(ratio.x), 0.0f);  // log2; clamp => sw<=1
        bl.y = fminf(BETA.y * __builtin_amdgcn_logf(ratio.y), 0.0f);
        v2f sw;
        sw.x = __builtin_amdgcn_exp2f(bl.x);
        sw.y = __builtin_amdgcn_exp2f(bl.y);
        const v2f rt = RAIN + tosoil;
        const v2f recharge = rt * sw;
        SM = SM + rt - recharge;
        const v2f excess = vmaxs(SM - FC, 0.0f);
        SM = vmin(SM, FC);                            // == SM - excess
        const v2f pet2  = bc(PET);
        const v2f ETact = vmin3(SM, (SM * invLPFC) * pet2, pet2);  // == min(SM, PET*clip(SM/(LP*FC),0,1))
        SM = vmaxs(SM - ETact, 1e-5f);

        // --- response routine (refactored: Q0+Q1 == SUZ2 - SUZ4) ---
        SUZ = SUZ + recharge + excess;
        const v2f PERC = vmin(SUZ, PERCc);
        const v2f SUZ2 = vmaxs(SUZ - PERCc, 0.0f);    // == SUZ - PERC
        const v2f SUZ3 = vmin(SUZ2, SUZ2 - K0 * (SUZ2 - UZL));  // == SUZ2 - Q0
        const v2f SUZ4 = SUZ3 * OMK1;                 // == SUZ3 - Q1
        SUZ = SUZ4;
        const v2f SLZ2 = SLZ + PERC;
        const v2f Q2 = K2 * SLZ2;
        SLZ = SLZ2 * OMK2;                            // == SLZ2 - Q2
        return (SUZ2 - SUZ4) + Q2;                    // Q0 + Q1 + Q2
    };

    // --- main loop: unguarded, unrolled by PFD; consume slot d then refill for t+PFD ---
    int tb = 0;
    for (; tb + PFD <= T; tb += PFD) {
        #pragma unroll
        for (int d = 0; d < PFD; ++d) {
            const v2f RAIN = RAINb[d], SNOW = SNOWb[d], MC = MCb[d], RC = RCb[d];
            const float PET = PETb[d];
            REFILL(d)                      // loads issue before the dependent step math
            const v2f Q = step(RAIN, SNOW, MC, RC, PET);
            *(v2f*)(ob + ooff) = Q;        // dwordx2 store (both chains)
            ooff += ostep;
        }
    }
    // --- tail: 0..PFD-1 guarded steps, static slot indices ---
    #pragma unroll
    for (int d = 0; d < PFD; ++d) {
        if (tb + d < T) {
            const v2f Q = step(RAINb[d], SNOWb[d], MCb[d], RCb[d], PETb[d]);
            *(v2f*)(ob + ooff) = Q;
            ooff += ostep;
        }
    }
    #undef REFILL
}

extern "C" void kernel_launch(void* const* d_in, const int* in_sizes, int n_in,
                              void* d_out, int out_size, void* d_ws, size_t ws_size,
                              hipStream_t stream) {
    const float* x    = (const float*)d_in[0];   // [T, G, 3]
    const float* praw = (const float*)d_in[1];   // [1, G, 12, 8]
    float* out = (float*)d_out;                  // [T, G, 8]

    const int G = in_sizes[1] / (NPAR * NM);     // 4000
    const int T = in_sizes[0] / (3 * G);         // 730

    const int npair = G * (NM / 2);              // 16000 threads, 2 chains each
    const int block = 64;
    const int grid = (npair + block - 1) / block;
    hbv_kernel<<<grid, block, 0, stream>>>(x, praw, out, G, T);
}

// Round 3
// 89.393 us; speedup vs baseline: 1.3543x; 1.3543x over previous
//
#include <hip/hip_runtime.h>
#include <math.h>
#include <stdint.h>

#define NM 8          // nmul
#define NPAR 12
#define PFD 8         // prefetch depth in timesteps (rolling register buffer)

__global__ __launch_bounds__(64, 1) void hbv_kernel(
    const float* __restrict__ x,      // [T, G, 3]  (prcp, tmean, pet)
    const float* __restrict__ praw,   // [1, G, 12, NM] in [0,1)
    float* __restrict__ out,          // [T, G, NM]
    int G, int T)
{
    const int tid = blockIdx.x * blockDim.x + threadIdx.x;
    const int total = G * NM;                // 1 chain per lane
    if (tid >= total) return;
    const int g = tid >> 3;                  // / NM
    const int m = tid & 7;                   // % NM

    // Parameter bounds: BETA, FC, K0, K1, K2, LP, PERC, UZL, TT, CFMAX, CFR, CWH
    const float lb[NPAR] = {1.0f, 50.0f, 0.05f, 0.01f, 0.001f, 0.2f, 0.0f, 0.0f, -2.5f, 0.5f, 0.0f, 0.0f};
    const float ub[NPAR] = {6.0f, 1000.0f, 0.9f, 0.5f, 0.2f, 1.0f, 10.0f, 100.0f, 2.5f, 10.0f, 0.1f, 0.2f};

    float p[NPAR];
    const float* pr = praw + (size_t)g * (NPAR * NM) + m;
    #pragma unroll
    for (int i = 0; i < NPAR; ++i) p[i] = pr[i * NM] * (ub[i] - lb[i]) + lb[i];

    const float BETA = p[0], FC = p[1], K0 = p[2], K1 = p[3], K2 = p[4], LP = p[5],
                PERCc = p[6], UZL = p[7], TT = p[8], CFMAX = p[9], CFR = p[10], CWH = p[11];

    const float invFC       = 1.0f / FC;
    const float invLPFC     = 1.0f / (LP * FC);
    const float CFMAX_TT    = CFMAX * TT;
    const float CFRCFMAX    = CFR * CFMAX;
    const float CFRCFMAX_TT = CFRCFMAX * TT;
    const float OMK1        = 1.0f - K1;
    const float OMK2        = 1.0f - K2;

    float SNOWPACK = 0.001f, MELTWATER = 0.001f, SM = 0.001f, SUZ = 0.001f, SLZ = 0.001f;

    // 32-bit byte offsets from uniform (SGPR) bases -> saddr-form loads/stores
    const char* xb = (const char*)x;
    char* ob = (char*)out;
    const uint32_t xstep = (uint32_t)G * 12u;                 // bytes per timestep in x
    uint32_t poff = (uint32_t)g * 12u;
    const uint32_t xmax  = poff + (uint32_t)(T - 1) * xstep;  // clamp target (last valid row)
    uint32_t ooff = (uint32_t)tid * 4u;
    const uint32_t ostep = (uint32_t)(G * NM) * 4u;

    // --- rolling forcing buffer; state-independent precompute hoisted into refill ---
    float Rb[PFD], Sb[PFD], MCb[PFD], RCb[PFD], Eb[PFD];

    // refill slot d from byte offset poff, then advance poff with branch-free clamp
    #define REFILL(d)                                                          \
    {                                                                          \
        const float* a_ = (const float*)(xb + poff);                           \
        const float P_  = a_[0];   /* adjacent dwords -> global_load_dwordx3 */\
        const float Tt_ = a_[1];                                               \
        Eb[d]           = a_[2];                                               \
        const float r_  = (Tt_ >= TT) ? P_ : 0.0f;                             \
        Rb[d] = r_;                                                            \
        Sb[d] = P_ - r_;                                                       \
        MCb[d] = fmaxf(fmaf(CFMAX, Tt_, -CFMAX_TT), 0.0f);                     \
        RCb[d] = fmaxf(fmaf(-CFRCFMAX, Tt_, CFRCFMAX_TT), 0.0f);               \
        const uint32_t nx_ = poff + xstep;                                     \
        poff = (nx_ < xmax) ? nx_ : xmax;                                      \
    }

    #pragma unroll
    for (int d = 0; d < PFD; ++d) REFILL(d)

    auto step = [&](float RAIN, float SNOW, float meltcap, float refrcap, float PET) -> float {
        // --- snow routine (caps pre-clamped at refill) ---
        SNOWPACK += SNOW;
        const float melt = fminf(meltcap, SNOWPACK);
        MELTWATER += melt;
        SNOWPACK  -= melt;
        const float refr = fminf(refrcap, MELTWATER);
        SNOWPACK  += refr;
        MELTWATER -= refr;
        const float cwhsp  = CWH * SNOWPACK;
        const float tosoil = fmaxf(MELTWATER - cwhsp, 0.0f);
        MELTWATER = fminf(MELTWATER, cwhsp);             // == MELTWATER - tosoil

        // --- soil routine ---
        const float lg = __builtin_amdgcn_logf(SM * invFC);   // log2; ratio in (0,1]
        const float bl = fminf(BETA * lg, 0.0f);              // clamp => sw <= 1
        const float sw = __builtin_amdgcn_exp2f(bl);
        const float rt = RAIN + tosoil;
        const float recharge = rt * sw;
        SM = SM + rt - recharge;
        const float excess = fmaxf(SM - FC, 0.0f);
        SM = fminf(SM, FC);                               // == SM - excess
        const float ETact = fminf(fminf(SM, SM * invLPFC * PET), PET);  // v_min3
        SM = fmaxf(SM - ETact, 1e-5f);

        // --- response routine (Q0+Q1 == SUZ2 - SUZ4) ---
        SUZ = SUZ + recharge + excess;
        const float PERC = fminf(SUZ, PERCc);
        const float SUZ2 = fmaxf(SUZ - PERCc, 0.0f);      // == SUZ - PERC
        const float SUZ3 = fminf(SUZ2, fmaf(-K0, SUZ2 - UZL, SUZ2));  // == SUZ2 - Q0
        const float SUZ4 = SUZ3 * OMK1;                   // == SUZ3 - Q1
        SUZ = SUZ4;
        const float SLZ2 = SLZ + PERC;
        const float Q2 = K2 * SLZ2;
        SLZ = SLZ2 * OMK2;                                // == SLZ2 - Q2
        return (SUZ2 - SUZ4) + Q2;                        // Q0 + Q1 + Q2
    };

    // --- main loop: unguarded, unrolled by PFD; consume slot d then refill for t+PFD ---
    int tb = 0;
    for (; tb + PFD <= T; tb += PFD) {
        #pragma unroll
        for (int d = 0; d < PFD; ++d) {
            const float R = Rb[d], S = Sb[d], MC = MCb[d], RC = RCb[d], E = Eb[d];
            REFILL(d)                       // loads issue before the dependent step math
            const float Q = step(R, S, MC, RC, E);
            *(float*)(ob + ooff) = Q;       // 64 consecutive floats per wave: coalesced
            ooff += ostep;
        }
    }
    // --- tail: 0..PFD-1 guarded steps, static slot indices ---
    #pragma unroll
    for (int d = 0; d < PFD; ++d) {
        if (tb + d < T) {
            const float Q = step(Rb[d], Sb[d], MCb[d], RCb[d], Eb[d]);
            *(float*)(ob + ooff) = Q;
            ooff += ostep;
        }
    }
    #undef REFILL
}

extern "C" void kernel_launch(void* const* d_in, const int* in_sizes, int n_in,
                              void* d_out, int out_size, void* d_ws, size_t ws_size,
                              hipStream_t stream) {
    const float* x    = (const float*)d_in[0];   // [T, G, 3]
    const float* praw = (const float*)d_in[1];   // [1, G, 12, 8]
    float* out = (float*)d_out;                  // [T, G, 8]

    const int G = in_sizes[1] / (NPAR * NM);     // 4000
    const int T = in_sizes[0] / (3 * G);         // 730

    const int total = G * NM;                    // 32000 threads, 1 chain each
    const int block = 64;
    const int grid = (total + block - 1) / block;
    hbv_kernel<<<grid, block, 0, stream>>>(x, praw, out, G, T);
}